// Round 1
// baseline (217.255 us; speedup 1.0000x reference)
//
#include <hip/hip_runtime.h>

typedef _Float16 f16x8 __attribute__((ext_vector_type(8)));
typedef float f32x4 __attribute__((ext_vector_type(4)));

// ---------------- conv1: (24,3,64,64) -> (24,32,32,32), stride2 SAME(lo=0,hi=1), relu
__global__ void conv1_k(const float* __restrict__ sx, const float* __restrict__ qx,
                        const float* __restrict__ w, const float* __restrict__ bias,
                        float* __restrict__ out) {
    int n  = blockIdx.x >> 5;   // 0..23
    int oc = blockIdx.x & 31;   // 0..31
    int bi = n / 6, si = n % 6;
    const float* inp = (si < 5) ? sx + (size_t)((bi*5+si)*3)*4096
                                : qx + (size_t)(bi*3)*4096;
    __shared__ float wl[27];
    __shared__ float bl;
    if (threadIdx.x < 27) wl[threadIdx.x] = w[oc*27 + threadIdx.x];
    if (threadIdx.x == 0) bl = bias[oc];
    __syncthreads();
    for (int idx = threadIdx.x; idx < 1024; idx += 256) {
        int oy = idx >> 5, ox = idx & 31;
        float acc = bl;
        #pragma unroll
        for (int ic = 0; ic < 3; ic++) {
            const float* ip = inp + ic*4096;
            #pragma unroll
            for (int dy = 0; dy < 3; dy++) {
                int iy = 2*oy + dy;
                if (iy >= 64) continue;
                #pragma unroll
                for (int dx = 0; dx < 3; dx++) {
                    int ix = 2*ox + dx;
                    if (ix >= 64) continue;
                    acc += ip[iy*64+ix] * wl[ic*9 + dy*3 + dx];
                }
            }
        }
        out[(size_t)(n*32+oc)*1024 + idx] = fmaxf(acc, 0.f);
    }
}

// ---------------- conv2: (24,32,32,32) -> (24,48,16,16), oc-group=4
__global__ void conv2_k(const float* __restrict__ in, const float* __restrict__ w,
                        const float* __restrict__ bias, float* __restrict__ out) {
    int n   = blockIdx.x / 12;
    int ocg = blockIdx.x % 12;      // oc = ocg*4 + ol
    __shared__ float wl[4*32*9];    // 1152
    for (int e = threadIdx.x; e < 1152; e += 256) wl[e] = w[ocg*4*288 + e];
    __syncthreads();
    int oy = threadIdx.x >> 4, ox = threadIdx.x & 15;
    float a0 = bias[ocg*4+0], a1 = bias[ocg*4+1], a2 = bias[ocg*4+2], a3 = bias[ocg*4+3];
    const float* ib = in + (size_t)n*32*1024;
    for (int ic = 0; ic < 32; ic++) {
        const float* ip = ib + ic*1024;
        float tap[9];
        #pragma unroll
        for (int dy = 0; dy < 3; dy++)
            #pragma unroll
            for (int dx = 0; dx < 3; dx++) {
                int iy = 2*oy+dy, ix = 2*ox+dx;
                tap[dy*3+dx] = (iy < 32 && ix < 32) ? ip[iy*32+ix] : 0.f;
            }
        #pragma unroll
        for (int t = 0; t < 9; t++) {
            a0 += tap[t]*wl[0*288 + ic*9 + t];
            a1 += tap[t]*wl[1*288 + ic*9 + t];
            a2 += tap[t]*wl[2*288 + ic*9 + t];
            a3 += tap[t]*wl[3*288 + ic*9 + t];
        }
    }
    size_t ob = (size_t)(n*48 + ocg*4)*256 + threadIdx.x;
    out[ob        ] = fmaxf(a0, 0.f);
    out[ob + 256  ] = fmaxf(a1, 0.f);
    out[ob + 512  ] = fmaxf(a2, 0.f);
    out[ob + 768  ] = fmaxf(a3, 0.f);
}

// ---------------- conv3: (24,48,16,16) -> (24,64,8,8), oc-group=8 (2 oc per thread)
__global__ void conv3_k(const float* __restrict__ in, const float* __restrict__ w,
                        const float* __restrict__ bias, float* __restrict__ out) {
    int n   = blockIdx.x >> 3;
    int ocg = blockIdx.x & 7;      // oc = ocg*8 + ol, ol = osub*2 + {0,1}
    __shared__ float wl[8*48*9];   // 3456
    for (int e = threadIdx.x; e < 3456; e += 256) wl[e] = w[ocg*8*432 + e];
    __syncthreads();
    int pix = threadIdx.x & 63, osub = threadIdx.x >> 6;
    int oy = pix >> 3, ox = pix & 7;
    int ol0 = osub*2;
    float a0 = bias[ocg*8 + ol0], a1 = bias[ocg*8 + ol0 + 1];
    const float* ib = in + (size_t)n*48*256;
    for (int ic = 0; ic < 48; ic++) {
        const float* ip = ib + ic*256;
        float tap[9];
        #pragma unroll
        for (int dy = 0; dy < 3; dy++)
            #pragma unroll
            for (int dx = 0; dx < 3; dx++) {
                int iy = 2*oy+dy, ix = 2*ox+dx;
                tap[dy*3+dx] = (iy < 16 && ix < 16) ? ip[iy*16+ix] : 0.f;
            }
        #pragma unroll
        for (int t = 0; t < 9; t++) {
            a0 += tap[t]*wl[ ol0   *432 + ic*9 + t];
            a1 += tap[t]*wl[(ol0+1)*432 + ic*9 + t];
        }
    }
    out[(size_t)(n*64 + ocg*8 + ol0  )*64 + pix] = fmaxf(a0, 0.f);
    out[(size_t)(n*64 + ocg*8 + ol0+1)*64 + pix] = fmaxf(a1, 0.f);
}

// ---------------- cls head: meanpool -> logits -> log_softmax -> gather label -> mean
__global__ void cls_k(const float* __restrict__ feat3, const int* __restrict__ sy,
                      const int* __restrict__ qy, const float* __restrict__ Wlog,
                      const float* __restrict__ blog, float* __restrict__ out0) {
    __shared__ float mf[24*64];
    __shared__ float lg[24*64];
    __shared__ float rv[24];
    int tid = threadIdx.x;
    for (int e = tid; e < 1536; e += 256) {
        const float* p = feat3 + (size_t)e*64;
        float s = 0.f;
        for (int k = 0; k < 64; k++) s += p[k];
        mf[e] = s * (1.f/64.f);
    }
    __syncthreads();
    for (int e = tid; e < 1536; e += 256) {
        int n = e >> 6, cl = e & 63;
        float s = blog[cl];
        for (int c = 0; c < 64; c++) s += mf[n*64+c]*Wlog[c*64+cl];
        lg[e] = s;
    }
    __syncthreads();
    if (tid < 24) {
        int bi = tid/6, si = tid%6;
        int lab = (si < 5) ? sy[bi*5+si] : qy[bi];
        float mx = -1e30f;
        for (int c = 0; c < 64; c++) mx = fmaxf(mx, lg[tid*64+c]);
        float se = 0.f;
        for (int c = 0; c < 64; c++) se += expf(lg[tid*64+c]-mx);
        rv[tid] = -(lg[tid*64+lab] - mx - logf(se));
    }
    __syncthreads();
    if (tid == 0) {
        float s = 0.f;
        for (int k = 0; k < 24; k++) s += rv[k];
        out0[0] = s * (1.f/24.f);
    }
}

// ---------------- u,v: a(b,s,64,66) @ Wg1[:66]/Wg1[66:] -> (b,s,64,128)
__global__ void uv_k(const float* __restrict__ feat3, const float* __restrict__ Wg1,
                     const float* __restrict__ bg1, float* __restrict__ u,
                     float* __restrict__ v) {
    int bs = blockIdx.x >> 4;    // 0..23
    int pg = blockIdx.x & 15;    // p-group of 4
    __shared__ float a4[4][66];
    int tid = threadIdx.x;       // 128
    for (int e = tid; e < 264; e += 128) {
        int pl = e / 66, c = e % 66;
        int p = pg*4 + pl;
        float vv;
        if (c < 64)      vv = feat3[(size_t)(bs*64 + c)*64 + p];
        else if (c == 64) vv = (float)(p >> 3) * 0.125f;
        else              vv = (float)(p & 7) * 0.125f;
        a4[pl][c] = vv;
    }
    __syncthreads();
    float us[4] = {0.f,0.f,0.f,0.f};
    float bg = bg1[tid];
    float vs[4] = {bg,bg,bg,bg};
    for (int c = 0; c < 66; c++) {
        float wa = Wg1[c*128 + tid];
        float wb = Wg1[(66+c)*128 + tid];
        #pragma unroll
        for (int pl = 0; pl < 4; pl++) {
            us[pl] += a4[pl][c]*wa;
            vs[pl] += a4[pl][c]*wb;
        }
    }
    #pragma unroll
    for (int pl = 0; pl < 4; pl++) {
        int p = pg*4 + pl;
        u[(size_t)(bs*64+p)*128 + tid] = us[pl];
        v[(size_t)(bs*64+p)*128 + tid] = vs[pl];
    }
}

// ---------------- relation core: per (b,j,i): x_f = sum_{p,q} relu(relu(u_i_p+v_j_q)@Wg2+bg2)
// then score = sigmoid(relu(x_f@Wf1+bf1)@Wf2+bf2). f16 MFMA 16x16x32.
__global__ void __launch_bounds__(256) rel_k(
        const float* __restrict__ u, const float* __restrict__ v,
        const float* __restrict__ Wg2, const float* __restrict__ bg2,
        const float* __restrict__ Wf1, const float* __restrict__ bf1,
        const float* __restrict__ Wf2, const float* __restrict__ bf2,
        float* __restrict__ Pmat) {
    __shared__ __align__(16) float Uld[64*128];
    __shared__ __align__(16) float Vld[64*128];
    __shared__ float xfred[4][64];
    __shared__ float xfl[64];
    __shared__ float hidl[16];

    int cb = blockIdx.x;
    int b = cb / 36, rem = cb % 36;
    int j = rem / 6, i = rem % 6;
    int tid  = threadIdx.x;
    int wv   = tid >> 6, lane = tid & 63;
    int col  = lane & 15, quad = lane >> 4;

    const float* ub = u + (size_t)(b*6 + i)*8192;
    const float* vb = v + (size_t)(b*6 + j)*8192;
    for (int e = tid*4; e < 8192; e += 1024) {
        *(f32x4*)&Uld[e] = *(const f32x4*)&ub[e];
        *(f32x4*)&Vld[e] = *(const f32x4*)&vb[e];
    }

    // B fragments: Wg2 (128x64) -> lane holds B[k=kt*32+quad*8+jj][n=nt*16+col]
    f16x8 bf[4][4];
    #pragma unroll
    for (int kt = 0; kt < 4; kt++)
        #pragma unroll
        for (int nt = 0; nt < 4; nt++) {
            f16x8 t;
            #pragma unroll
            for (int jj = 0; jj < 8; jj++) {
                int k = kt*32 + quad*8 + jj;
                t[jj] = (_Float16)Wg2[k*64 + nt*16 + col];
            }
            bf[kt][nt] = t;
        }
    float bgv[4];
    #pragma unroll
    for (int nt = 0; nt < 4; nt++) bgv[nt] = bg2[nt*16 + col];

    __syncthreads();

    // per-lane fixed U slice: p = wv*16 + (lane&15) (A-row m), k = kt*32+quad*8+jj
    int p_lane = wv*16 + col;
    float uval[32];
    {
        const float* up = &Uld[p_lane*128 + quad*8];
        #pragma unroll
        for (int kt = 0; kt < 4; kt++) {
            f32x4 x = *(const f32x4*)&up[kt*32];
            f32x4 y = *(const f32x4*)&up[kt*32 + 4];
            #pragma unroll
            for (int r = 0; r < 4; r++) { uval[kt*8+r] = x[r]; uval[kt*8+4+r] = y[r]; }
        }
    }

    float sums[4] = {0.f,0.f,0.f,0.f};
    for (int q = 0; q < 64; q++) {
        const float* vp = &Vld[q*128 + quad*8];
        f32x4 acc[4];
        #pragma unroll
        for (int nt = 0; nt < 4; nt++) acc[nt] = (f32x4){0.f,0.f,0.f,0.f};
        #pragma unroll
        for (int kt = 0; kt < 4; kt++) {
            f32x4 x = *(const f32x4*)&vp[kt*32];
            f32x4 y = *(const f32x4*)&vp[kt*32 + 4];
            f16x8 af;
            #pragma unroll
            for (int r = 0; r < 4; r++) {
                af[r]   = (_Float16)fmaxf(uval[kt*8+r]   + x[r], 0.f);
                af[4+r] = (_Float16)fmaxf(uval[kt*8+4+r] + y[r], 0.f);
            }
            #pragma unroll
            for (int nt = 0; nt < 4; nt++)
                acc[nt] = __builtin_amdgcn_mfma_f32_16x16x32_f16(af, bf[kt][nt], acc[nt], 0, 0, 0);
        }
        #pragma unroll
        for (int nt = 0; nt < 4; nt++)
            #pragma unroll
            for (int rr = 0; rr < 4; rr++)
                sums[nt] += fmaxf(acc[nt][rr] + bgv[nt], 0.f);
    }

    // reduce rows across quads (cols live at lane&15 in every quad)
    #pragma unroll
    for (int nt = 0; nt < 4; nt++) {
        sums[nt] += __shfl_xor(sums[nt], 16, 64);
        sums[nt] += __shfl_xor(sums[nt], 32, 64);
    }
    if (lane < 16) {
        #pragma unroll
        for (int nt = 0; nt < 4; nt++) xfred[wv][nt*16 + lane] = sums[nt];
    }
    __syncthreads();
    if (tid < 64) xfl[tid] = xfred[0][tid] + xfred[1][tid] + xfred[2][tid] + xfred[3][tid];
    __syncthreads();
    if (tid < 16) {
        float s = bf1[tid];
        for (int c = 0; c < 64; c++) s += xfl[c]*Wf1[c*16 + tid];
        hidl[tid] = fmaxf(s, 0.f);
    }
    __syncthreads();
    if (tid == 0) {
        float s = bf2[0];
        #pragma unroll
        for (int t2 = 0; t2 < 16; t2++) s += hidl[t2]*Wf2[t2];
        Pmat[cb] = 1.f/(1.f + expf(-s));
    }
}

// ---------------- final losses
__global__ void loss_k(const float* __restrict__ Pmat, const int* __restrict__ sy,
                       const int* __restrict__ qy, float* __restrict__ out) {
    __shared__ float Pm[144];
    __shared__ int lab[24];
    __shared__ float red[256];
    __shared__ float ratio[4];
    int tid = threadIdx.x;
    if (tid < 144) Pm[tid] = Pmat[tid];
    if (tid < 24) { int bi = tid/6, si = tid%6; lab[tid] = (si < 5) ? sy[bi*5+si] : qy[bi]; }
    __syncthreads();
    float e = 0.f;
    if (tid < 144) {
        int b = tid/36, r = tid%36, jj = r/6, ii = r%6;
        float y = (lab[b*6+jj] == lab[b*6+ii]) ? 1.f : 0.f;
        float d = Pm[tid] - y;
        e = d*d;
    }
    red[tid] = e;
    __syncthreads();
    for (int s = 128; s > 0; s >>= 1) {
        if (tid < s) red[tid] += red[tid+s];
        __syncthreads();
    }
    if (tid < 4) {
        float s2 = 0.f, a2 = 0.f;
        for (int jj = 0; jj < 6; jj++)
            for (int ii = 0; ii < 6; ii++) {
                float pa = Pm[tid*36 + jj*6 + ii], pb = Pm[tid*36 + ii*6 + jj];
                float sm = 0.5f*(pa+pb), an = 0.5f*(pa-pb);
                s2 += sm*sm; a2 += an*an;
            }
        float sn = sqrtf(s2), anq = sqrtf(a2);
        ratio[tid] = (sn - anq)/(sn + anq);
    }
    __syncthreads();
    if (tid == 0) {
        float sl = 0.25f*(ratio[0]+ratio[1]+ratio[2]+ratio[3]);
        float euc = red[0] * (1.f/144.f);
        out[1] = euc - 0.1f*sl;
        out[2] = sl;
    }
}

extern "C" void kernel_launch(void* const* d_in, const int* in_sizes, int n_in,
                              void* d_out, int out_size, void* d_ws, size_t ws_size,
                              hipStream_t stream) {
    const float* sx   = (const float*)d_in[0];
    const int*   sy   = (const int*)  d_in[1];
    const float* qx   = (const float*)d_in[2];
    const int*   qy   = (const int*)  d_in[3];
    const float* k1   = (const float*)d_in[4];
    const float* bc1  = (const float*)d_in[5];
    const float* k2   = (const float*)d_in[6];
    const float* bc2  = (const float*)d_in[7];
    const float* k3   = (const float*)d_in[8];
    const float* bc3  = (const float*)d_in[9];
    const float* Wlog = (const float*)d_in[10];
    const float* blog = (const float*)d_in[11];
    const float* Wg1  = (const float*)d_in[12];
    const float* bg1  = (const float*)d_in[13];
    const float* Wg2  = (const float*)d_in[14];
    const float* bg2  = (const float*)d_in[15];
    const float* Wf1  = (const float*)d_in[16];
    const float* bf1  = (const float*)d_in[17];
    const float* Wf2  = (const float*)d_in[18];
    const float* bf2  = (const float*)d_in[19];

    float* ws    = (float*)d_ws;
    float* feat1 = ws;                    // 24*32*32*32 = 786432
    float* feat2 = feat1 + 786432;        // 24*48*16*16 = 294912
    float* feat3 = feat2 + 294912;        // 24*64*8*8   = 98304
    float* uu    = feat3 + 98304;         // 24*64*128   = 196608
    float* vv    = uu    + 196608;        // 196608
    float* Pm    = vv    + 196608;        // 144
    float* out   = (float*)d_out;

    conv1_k<<<24*32, 256, 0, stream>>>(sx, qx, k1, bc1, feat1);
    conv2_k<<<24*12, 256, 0, stream>>>(feat1, k2, bc2, feat2);
    conv3_k<<<24*8,  256, 0, stream>>>(feat2, k3, bc3, feat3);
    cls_k  <<<1,     256, 0, stream>>>(feat3, sy, qy, Wlog, blog, out);
    uv_k   <<<24*16, 128, 0, stream>>>(feat3, Wg1, bg1, uu, vv);
    rel_k  <<<144,   256, 0, stream>>>(uu, vv, Wg2, bg2, Wf1, bf1, Wf2, bf2, Pm);
    loss_k <<<1,     256, 0, stream>>>(Pm, sy, qy, out);
}

// Round 2
// 190.484 us; speedup vs baseline: 1.1405x; 1.1405x over previous
//
#include <hip/hip_runtime.h>

typedef _Float16 f16x8 __attribute__((ext_vector_type(8)));
typedef float f32x4 __attribute__((ext_vector_type(4)));

// ---------------- conv1: (24,3,64,64) -> (24,32,32,32), stride2 SAME, relu
// block 768 additionally packs Wg2 into f16 MFMA B-fragment order.
__global__ void conv1_k(const float* __restrict__ sx, const float* __restrict__ qx,
                        const float* __restrict__ w, const float* __restrict__ bias,
                        float* __restrict__ out,
                        const float* __restrict__ Wg2, _Float16* __restrict__ W2h) {
    if (blockIdx.x == 768) {
        // pack: W2h[((kt*4+nt)*64 + lane)*8 + jj] = Wg2[(kt*32+quad*8+jj)*64 + nt*16+col]
        for (int s = 0; s < 4; s++) {
            int slot = threadIdx.x + 256*s;      // 0..1023
            int tile = slot >> 6, lane = slot & 63;
            int kt = tile >> 2, nt = tile & 3;
            int quad = lane >> 4, col = lane & 15;
            f16x8 t;
            #pragma unroll
            for (int jj = 0; jj < 8; jj++)
                t[jj] = (_Float16)Wg2[(kt*32 + quad*8 + jj)*64 + nt*16 + col];
            *(f16x8*)&W2h[slot*8] = t;
        }
        return;
    }
    int n  = blockIdx.x >> 5;   // 0..23
    int oc = blockIdx.x & 31;   // 0..31
    int bi = n / 6, si = n % 6;
    const float* inp = (si < 5) ? sx + (size_t)((bi*5+si)*3)*4096
                                : qx + (size_t)(bi*3)*4096;
    __shared__ float wl[27];
    __shared__ float bl;
    if (threadIdx.x < 27) wl[threadIdx.x] = w[oc*27 + threadIdx.x];
    if (threadIdx.x == 0) bl = bias[oc];
    __syncthreads();
    for (int idx = threadIdx.x; idx < 1024; idx += 256) {
        int oy = idx >> 5, ox = idx & 31;
        float acc = bl;
        #pragma unroll
        for (int ic = 0; ic < 3; ic++) {
            const float* ip = inp + ic*4096;
            #pragma unroll
            for (int dy = 0; dy < 3; dy++) {
                int iy = 2*oy + dy;
                if (iy >= 64) continue;
                #pragma unroll
                for (int dx = 0; dx < 3; dx++) {
                    int ix = 2*ox + dx;
                    if (ix >= 64) continue;
                    acc += ip[iy*64+ix] * wl[ic*9 + dy*3 + dx];
                }
            }
        }
        out[(size_t)(n*32+oc)*1024 + idx] = fmaxf(acc, 0.f);
    }
}

// ---------------- conv2: (24,32,32,32) -> (24,48,16,16), oc-group=4
__global__ void conv2_k(const float* __restrict__ in, const float* __restrict__ w,
                        const float* __restrict__ bias, float* __restrict__ out) {
    int n   = blockIdx.x / 12;
    int ocg = blockIdx.x % 12;
    __shared__ float wl[4*32*9];
    for (int e = threadIdx.x; e < 1152; e += 256) wl[e] = w[ocg*4*288 + e];
    __syncthreads();
    int oy = threadIdx.x >> 4, ox = threadIdx.x & 15;
    float a0 = bias[ocg*4+0], a1 = bias[ocg*4+1], a2 = bias[ocg*4+2], a3 = bias[ocg*4+3];
    const float* ib = in + (size_t)n*32*1024;
    for (int ic = 0; ic < 32; ic++) {
        const float* ip = ib + ic*1024;
        float tap[9];
        #pragma unroll
        for (int dy = 0; dy < 3; dy++)
            #pragma unroll
            for (int dx = 0; dx < 3; dx++) {
                int iy = 2*oy+dy, ix = 2*ox+dx;
                tap[dy*3+dx] = (iy < 32 && ix < 32) ? ip[iy*32+ix] : 0.f;
            }
        #pragma unroll
        for (int t = 0; t < 9; t++) {
            a0 += tap[t]*wl[0*288 + ic*9 + t];
            a1 += tap[t]*wl[1*288 + ic*9 + t];
            a2 += tap[t]*wl[2*288 + ic*9 + t];
            a3 += tap[t]*wl[3*288 + ic*9 + t];
        }
    }
    size_t ob = (size_t)(n*48 + ocg*4)*256 + threadIdx.x;
    out[ob        ] = fmaxf(a0, 0.f);
    out[ob + 256  ] = fmaxf(a1, 0.f);
    out[ob + 512  ] = fmaxf(a2, 0.f);
    out[ob + 768  ] = fmaxf(a3, 0.f);
}

// ---------------- conv3 + fused mean-pool: (24,48,16,16) -> (24,64,8,8) + mf(24,64)
__global__ void conv3_k(const float* __restrict__ in, const float* __restrict__ w,
                        const float* __restrict__ bias, float* __restrict__ out,
                        float* __restrict__ mf) {
    int n   = blockIdx.x >> 3;
    int ocg = blockIdx.x & 7;
    __shared__ float wl[8*48*9];
    for (int e = threadIdx.x; e < 3456; e += 256) wl[e] = w[ocg*8*432 + e];
    __syncthreads();
    int pix = threadIdx.x & 63, osub = threadIdx.x >> 6;
    int oy = pix >> 3, ox = pix & 7;
    int ol0 = osub*2;
    float a0 = bias[ocg*8 + ol0], a1 = bias[ocg*8 + ol0 + 1];
    const float* ib = in + (size_t)n*48*256;
    for (int ic = 0; ic < 48; ic++) {
        const float* ip = ib + ic*256;
        float tap[9];
        #pragma unroll
        for (int dy = 0; dy < 3; dy++)
            #pragma unroll
            for (int dx = 0; dx < 3; dx++) {
                int iy = 2*oy+dy, ix = 2*ox+dx;
                tap[dy*3+dx] = (iy < 16 && ix < 16) ? ip[iy*16+ix] : 0.f;
            }
        #pragma unroll
        for (int t = 0; t < 9; t++) {
            a0 += tap[t]*wl[ ol0   *432 + ic*9 + t];
            a1 += tap[t]*wl[(ol0+1)*432 + ic*9 + t];
        }
    }
    float r0 = fmaxf(a0, 0.f), r1 = fmaxf(a1, 0.f);
    out[(size_t)(n*64 + ocg*8 + ol0  )*64 + pix] = r0;
    out[(size_t)(n*64 + ocg*8 + ol0+1)*64 + pix] = r1;
    // wave (= osub) reduce over 64 pixels
    #pragma unroll
    for (int off = 32; off >= 1; off >>= 1) {
        r0 += __shfl_xor(r0, off, 64);
        r1 += __shfl_xor(r1, off, 64);
    }
    if (pix == 0) {
        mf[n*64 + ocg*8 + ol0    ] = r0 * (1.f/64.f);
        mf[n*64 + ocg*8 + ol0 + 1] = r1 * (1.f/64.f);
    }
}

// ---------------- uv (blocks 0..383, f16 out) + cls head (blocks 384..407)
__global__ void uvcls_k(const float* __restrict__ feat3, const float* __restrict__ Wg1,
                        const float* __restrict__ bg1, _Float16* __restrict__ u,
                        _Float16* __restrict__ v,
                        const float* __restrict__ mf, const int* __restrict__ sy,
                        const int* __restrict__ qy, const float* __restrict__ Wlog,
                        const float* __restrict__ blog, float* __restrict__ rv) {
    int tid = threadIdx.x;   // 128
    if (blockIdx.x >= 384) {
        // cls: one block per image n, lanes 0..63 = class index
        int n = blockIdx.x - 384;
        if (tid >= 64) return;
        int lane = tid;
        float s = blog[lane];
        for (int c = 0; c < 64; c++) s += mf[n*64 + c] * Wlog[c*64 + lane];
        float mx = s;
        #pragma unroll
        for (int off = 32; off >= 1; off >>= 1) mx = fmaxf(mx, __shfl_xor(mx, off, 64));
        float p = __expf(s - mx);
        float se = p;
        #pragma unroll
        for (int off = 32; off >= 1; off >>= 1) se += __shfl_xor(se, off, 64);
        int bi = n/6, si = n%6;
        int lab = (si < 5) ? sy[bi*5+si] : qy[bi];
        float s_lab = __shfl(s, lab, 64);
        if (lane == 0) rv[n] = -(s_lab - mx - __logf(se));
        return;
    }
    int bs = blockIdx.x >> 4;    // 0..23
    int pg = blockIdx.x & 15;    // p-group of 4
    __shared__ float a4[4][66];
    for (int e = tid; e < 264; e += 128) {
        int pl = e / 66, c = e % 66;
        int p = pg*4 + pl;
        float vv;
        if (c < 64)       vv = feat3[(size_t)(bs*64 + c)*64 + p];
        else if (c == 64) vv = (float)(p >> 3) * 0.125f;
        else              vv = (float)(p & 7) * 0.125f;
        a4[pl][c] = vv;
    }
    __syncthreads();
    float us[4] = {0.f,0.f,0.f,0.f};
    float bg = bg1[tid];
    float vs[4] = {bg,bg,bg,bg};
    for (int c = 0; c < 66; c++) {
        float wa = Wg1[c*128 + tid];
        float wb = Wg1[(66+c)*128 + tid];
        #pragma unroll
        for (int pl = 0; pl < 4; pl++) {
            us[pl] += a4[pl][c]*wa;
            vs[pl] += a4[pl][c]*wb;
        }
    }
    #pragma unroll
    for (int pl = 0; pl < 4; pl++) {
        int p = pg*4 + pl;
        u[(size_t)(bs*64+p)*128 + tid] = (_Float16)us[pl];
        v[(size_t)(bs*64+p)*128 + tid] = (_Float16)vs[pl];
    }
}

// ---------------- relation core, q-split x4: block = (cb, qc); writes xf partials
__global__ void __launch_bounds__(256) rel_k(
        const _Float16* __restrict__ U, const _Float16* __restrict__ V,
        const _Float16* __restrict__ W2h, const float* __restrict__ bg2,
        float* __restrict__ xfpart) {
    __shared__ __align__(16) _Float16 Vsh[16*128];
    __shared__ float xfred[4][64];

    int bx = blockIdx.x;
    int cb = bx >> 2, qc = bx & 3;
    int b = cb / 36, rem = cb % 36;
    int j = rem / 6, i = rem % 6;
    int tid  = threadIdx.x;
    int wv   = tid >> 6, lane = tid & 63;
    int col  = lane & 15, quad = lane >> 4;

    const _Float16* ub = U + (size_t)(b*6 + i)*8192;
    const _Float16* vb = V + (size_t)(b*6 + j)*8192 + qc*16*128;

    // stage V chunk (16 q-rows x 128 k) into LDS, coalesced
    *(f16x8*)&Vsh[tid*8] = *(const f16x8*)&vb[tid*8];

    // per-lane fixed U slice: p = wv*16+col, k = kt*32 + quad*8 + jj
    f16x8 uf[4];
    {
        const _Float16* up = ub + (wv*16 + col)*128 + quad*8;
        #pragma unroll
        for (int kt = 0; kt < 4; kt++) uf[kt] = *(const f16x8*)&up[kt*32];
    }
    // pre-packed B fragments, coalesced dwordx4 loads
    f16x8 bf[4][4];
    #pragma unroll
    for (int kt = 0; kt < 4; kt++)
        #pragma unroll
        for (int nt = 0; nt < 4; nt++)
            bf[kt][nt] = *(const f16x8*)&W2h[(size_t)(((kt*4+nt)*64) + lane)*8];
    float bgv[4];
    #pragma unroll
    for (int nt = 0; nt < 4; nt++) bgv[nt] = bg2[nt*16 + col];

    __syncthreads();

    float sums[4] = {0.f,0.f,0.f,0.f};
    for (int q = 0; q < 16; q++) {
        const _Float16* vp = &Vsh[q*128 + quad*8];
        f32x4 acc[4];
        #pragma unroll
        for (int nt = 0; nt < 4; nt++)
            acc[nt] = (f32x4){bgv[nt], bgv[nt], bgv[nt], bgv[nt]};   // bias folded into C
        #pragma unroll
        for (int kt = 0; kt < 4; kt++) {
            f16x8 vf = *(const f16x8*)&vp[kt*32];
            f16x8 af = uf[kt] + vf;                                   // v_pk_add_f16
            af = __builtin_elementwise_max(af, (f16x8){0,0,0,0,0,0,0,0}); // v_pk_max_f16
            #pragma unroll
            for (int nt = 0; nt < 4; nt++)
                acc[nt] = __builtin_amdgcn_mfma_f32_16x16x32_f16(af, bf[kt][nt], acc[nt], 0, 0, 0);
        }
        #pragma unroll
        for (int nt = 0; nt < 4; nt++)
            #pragma unroll
            for (int rr = 0; rr < 4; rr++)
                sums[nt] += fmaxf(acc[nt][rr], 0.f);
    }

    #pragma unroll
    for (int nt = 0; nt < 4; nt++) {
        sums[nt] += __shfl_xor(sums[nt], 16, 64);
        sums[nt] += __shfl_xor(sums[nt], 32, 64);
    }
    if (lane < 16) {
        #pragma unroll
        for (int nt = 0; nt < 4; nt++) xfred[wv][nt*16 + lane] = sums[nt];
    }
    __syncthreads();
    if (tid < 64)
        xfpart[(size_t)bx*64 + tid] = xfred[0][tid] + xfred[1][tid] + xfred[2][tid] + xfred[3][tid];
}

// ---------------- score head + all losses
__global__ void loss_k(const float* __restrict__ xfp, const float* __restrict__ rv,
                       const int* __restrict__ sy, const int* __restrict__ qy,
                       const float* __restrict__ Wf1, const float* __restrict__ bf1,
                       const float* __restrict__ Wf2, const float* __restrict__ bf2,
                       float* __restrict__ out) {
    __shared__ float Wf1sh[1024];
    __shared__ float wf2sh[16];
    __shared__ float bf1sh[16];
    __shared__ float Pm[144];
    __shared__ int lab[24];
    __shared__ float red[256];
    __shared__ float ratio[4];
    int tid = threadIdx.x;
    for (int e = tid; e < 1024; e += 256) Wf1sh[e] = Wf1[e];
    if (tid < 16) { wf2sh[tid] = Wf2[tid]; bf1sh[tid] = bf1[tid]; }
    if (tid < 24) { int bi = tid/6, si = tid%6; lab[tid] = (si < 5) ? sy[bi*5+si] : qy[bi]; }
    __syncthreads();
    if (tid < 144) {
        float hid[16];
        #pragma unroll
        for (int h = 0; h < 16; h++) hid[h] = bf1sh[h];
        const float* xb = xfp + (size_t)tid*4*64;
        for (int n = 0; n < 64; n++) {
            float x = xb[n] + xb[64+n] + xb[128+n] + xb[192+n];
            #pragma unroll
            for (int h = 0; h < 16; h++) hid[h] += x * Wf1sh[n*16 + h];
        }
        float sc = bf2[0];
        #pragma unroll
        for (int h = 0; h < 16; h++) sc += fmaxf(hid[h], 0.f) * wf2sh[h];
        Pm[tid] = 1.f/(1.f + __expf(-sc));
    }
    __syncthreads();
    float e = 0.f;
    if (tid < 144) {
        int b = tid/36, r = tid%36, jj = r/6, ii = r%6;
        float y = (lab[b*6+jj] == lab[b*6+ii]) ? 1.f : 0.f;
        float d = Pm[tid] - y;
        e = d*d;
    }
    red[tid] = e;
    __syncthreads();
    for (int s = 128; s > 0; s >>= 1) {
        if (tid < s) red[tid] += red[tid+s];
        __syncthreads();
    }
    if (tid < 4) {
        float s2 = 0.f, a2 = 0.f;
        for (int jj = 0; jj < 6; jj++)
            for (int ii = 0; ii < 6; ii++) {
                float pa = Pm[tid*36 + jj*6 + ii], pb = Pm[tid*36 + ii*6 + jj];
                float sm = 0.5f*(pa+pb), an = 0.5f*(pa-pb);
                s2 += sm*sm; a2 += an*an;
            }
        float sn = sqrtf(s2), anq = sqrtf(a2);
        ratio[tid] = (sn - anq)/(sn + anq);
    }
    __syncthreads();
    if (tid == 0) {
        float sl = 0.25f*(ratio[0]+ratio[1]+ratio[2]+ratio[3]);
        float euc = red[0] * (1.f/144.f);
        float cs = 0.f;
        for (int k = 0; k < 24; k++) cs += rv[k];
        out[0] = cs * (1.f/24.f);
        out[1] = euc - 0.1f*sl;
        out[2] = sl;
    }
}

extern "C" void kernel_launch(void* const* d_in, const int* in_sizes, int n_in,
                              void* d_out, int out_size, void* d_ws, size_t ws_size,
                              hipStream_t stream) {
    const float* sx   = (const float*)d_in[0];
    const int*   sy   = (const int*)  d_in[1];
    const float* qx   = (const float*)d_in[2];
    const int*   qy   = (const int*)  d_in[3];
    const float* k1   = (const float*)d_in[4];
    const float* bc1  = (const float*)d_in[5];
    const float* k2   = (const float*)d_in[6];
    const float* bc2  = (const float*)d_in[7];
    const float* k3   = (const float*)d_in[8];
    const float* bc3  = (const float*)d_in[9];
    const float* Wlog = (const float*)d_in[10];
    const float* blog = (const float*)d_in[11];
    const float* Wg1  = (const float*)d_in[12];
    const float* bg1  = (const float*)d_in[13];
    const float* Wg2  = (const float*)d_in[14];
    const float* bg2  = (const float*)d_in[15];
    const float* Wf1  = (const float*)d_in[16];
    const float* bf1  = (const float*)d_in[17];
    const float* Wf2  = (const float*)d_in[18];
    const float* bf2  = (const float*)d_in[19];

    float* ws    = (float*)d_ws;
    float* feat1 = ws;                    // 786432
    float* feat2 = feat1 + 786432;        // 294912
    float* feat3 = feat2 + 294912;        // 98304
    float* mf    = feat3 + 98304;         // 1536
    float* rv    = mf    + 1536;          // 32 (24 used)
    float* xfp   = rv    + 32;            // 576*64 = 36864
    _Float16* u16 = (_Float16*)(xfp + 36864);  // 196608 halves
    _Float16* v16 = u16 + 196608;              // 196608 halves
    _Float16* W2h = v16 + 196608;              // 8192 halves
    float* out   = (float*)d_out;

    conv1_k <<<769,    256, 0, stream>>>(sx, qx, k1, bc1, feat1, Wg2, W2h);
    conv2_k <<<24*12,  256, 0, stream>>>(feat1, k2, bc2, feat2);
    conv3_k <<<24*8,   256, 0, stream>>>(feat2, k3, bc3, feat3, mf);
    uvcls_k <<<408,    128, 0, stream>>>(feat3, Wg1, bg1, u16, v16,
                                         mf, sy, qy, Wlog, blog, rv);
    rel_k   <<<576,    256, 0, stream>>>(u16, v16, W2h, bg2, xfp);
    loss_k  <<<1,      256, 0, stream>>>(xfp, rv, sy, qy, Wf1, bf1, Wf2, bf2, out);
}